// Round 10
// baseline (673.063 us; speedup 1.0000x reference)
//
#include <hip/hip_runtime.h>
#include <hip/hip_bf16.h>
#include <cstdint>
#include <cstddef>

// AttentionLayerEnhance: B=4, L=S=2048, D=512, H=8, window=32.
// I/O: all inputs f32, both outputs f32. Internal: bf16 MFMA, f32 accum.
// Accounting (R3-R9): ~470us of dur_us is harness poison/restore; ours ~181us.
// R8 lesson: keep B LDS-staged (direct-global B regresses ~20us).
// R10 structure: overlap the 537MB attn zero-fill with the QKV GEMM (K2);
// band blocks overwritten by K4's band-writer (stream-ordered, race-free).
#define D_MODEL 512
#define N_HEADS 8
#define HDIM 64
#define SEQ 2048
#define B_SZ 4
#define M_TOT (B_SZ * SEQ)
#define ATTN_ROWS (B_SZ * N_HEADS * SEQ)
#define PROJ_ELEMS ((size_t)M_TOT * D_MODEL)

typedef __bf16 bf16x8 __attribute__((ext_vector_type(8)));
typedef float  f32x4  __attribute__((ext_vector_type(4)));

__device__ __forceinline__ unsigned short f2bf(float x) {
    __bf16 b = (__bf16)x;
    return __builtin_bit_cast(unsigned short, b);
}

// ---------------------------------------------------------------------------
// 512x512 transpose (f32 W[k][n] -> bf16 Wt[n][k]). z selects weight.
// ---------------------------------------------------------------------------
struct TransArgs {
    const float* W[4];
    unsigned short* Wt[4];
};

__global__ void transpose_k(TransArgs ta) {
    __shared__ float tile[32][33];
    const int z = blockIdx.z;
    const float* W = ta.W[z];
    unsigned short* Wt = ta.Wt[z];
    int x = blockIdx.x * 32 + threadIdx.x;
    int y0 = blockIdx.y * 32;
    for (int j = threadIdx.y; j < 32; j += 8)
        tile[j][threadIdx.x] = W[(size_t)(y0 + j) * D_MODEL + x];
    __syncthreads();
    int xo = blockIdx.y * 32 + threadIdx.x;
    int yo0 = blockIdx.x * 32;
    for (int j = threadIdx.y; j < 32; j += 8)
        Wt[(size_t)(yo0 + j) * D_MODEL + xo] = f2bf(tile[threadIdx.x][j]);
}

#define LDSTRIDE 72

// ---------------------------------------------------------------------------
// GEMM tile body (R7-proven): C[128,128] tile of A[M,512]*W + bias.
// A: f32, staged->bf16 in LDS. B (Wt[N,K] bf16): LDS-staged.
// 4 waves (2x2 of 64x64), mfma_f32_16x16x32_bf16, 4x4 acc/wave.
// ---------------------------------------------------------------------------
template <int F32OUT>
__device__ __forceinline__ void gemm_tile(
    const float* __restrict__ A, const unsigned short* __restrict__ Wt,
    const float* __restrict__ bias, void* __restrict__ C,
    int m0, int n0, unsigned short* lsA, unsigned short* lsB) {
    const int tid = threadIdx.x;
    const int lane = tid & 63;
    const int wid = tid >> 6;
    const int wm = (wid >> 1) * 64;
    const int wn = (wid & 1) * 64;
    const int lrow = lane & 15;
    const int quad = lane >> 4;

    f32x4 acc[4][4];
#pragma unroll
    for (int i = 0; i < 4; ++i)
#pragma unroll
        for (int j = 0; j < 4; ++j)
            acc[i][j] = (f32x4){0.f, 0.f, 0.f, 0.f};

    for (int kt = 0; kt < D_MODEL; kt += 64) {
        __syncthreads();
#pragma unroll
        for (int p = 0; p < 4; ++p) {
            int c = p * 256 + tid;
            int r = c >> 3;
            int col = (c & 7) << 3;
            const float* src = &A[(size_t)(m0 + r) * D_MODEL + kt + col];
            float4 a0 = *(const float4*)src;
            float4 a1 = *(const float4*)(src + 4);
            unsigned short t8[8];
            t8[0] = f2bf(a0.x); t8[1] = f2bf(a0.y); t8[2] = f2bf(a0.z); t8[3] = f2bf(a0.w);
            t8[4] = f2bf(a1.x); t8[5] = f2bf(a1.y); t8[6] = f2bf(a1.z); t8[7] = f2bf(a1.w);
            *(uint4*)&lsA[r * LDSTRIDE + col] = *(const uint4*)t8;
        }
#pragma unroll
        for (int p = 0; p < 4; ++p) {
            int c = p * 256 + tid;
            int r = c >> 3;
            int col = (c & 7) << 3;
            *(uint4*)&lsB[r * LDSTRIDE + col] =
                *(const uint4*)&Wt[(size_t)(n0 + r) * D_MODEL + kt + col];
        }
        __syncthreads();
#pragma unroll
        for (int ks = 0; ks < 2; ++ks) {
            const int ko = ks * 32 + quad * 8;
            bf16x8 af[4], bfr[4];
#pragma unroll
            for (int mt = 0; mt < 4; ++mt)
                af[mt] = *(const bf16x8*)&lsA[(wm + mt * 16 + lrow) * LDSTRIDE + ko];
#pragma unroll
            for (int nt = 0; nt < 4; ++nt)
                bfr[nt] = *(const bf16x8*)&lsB[(wn + nt * 16 + lrow) * LDSTRIDE + ko];
#pragma unroll
            for (int mt = 0; mt < 4; ++mt)
#pragma unroll
                for (int nt = 0; nt < 4; ++nt)
                    acc[mt][nt] = __builtin_amdgcn_mfma_f32_16x16x32_bf16(
                        af[mt], bfr[nt], acc[mt][nt], 0, 0, 0);
        }
    }

    // Epilogue: C/D layout col=lane&15, row=quad*4+reg (m89-verified).
#pragma unroll
    for (int nt = 0; nt < 4; ++nt) {
        const int gcol = n0 + wn + nt * 16 + lrow;
        const float bv = bias[gcol];
#pragma unroll
        for (int mt = 0; mt < 4; ++mt) {
            const int grow = m0 + wm + mt * 16 + quad * 4;
#pragma unroll
            for (int r = 0; r < 4; ++r) {
                const float v = acc[mt][nt][r] + bv;
                if (F32OUT)
                    __builtin_nontemporal_store(
                        v, &((float*)C)[(size_t)(grow + r) * D_MODEL + gcol]);
                else
                    ((unsigned short*)C)[(size_t)(grow + r) * D_MODEL + gcol] = f2bf(v);
            }
        }
    }
}

// ---------------------------------------------------------------------------
// K2: blocks 0..767 = QKV GEMM (dispatched first, pipeline-bound);
// blocks 768..1791 = zero-fill of the entire 537MB attn matrix (BW-bound,
// overlaps with the GEMM — the zeros depend on nothing). Band blocks get
// overwritten by K4's band-writer later in the stream.
// ---------------------------------------------------------------------------
struct GemmArgs {
    const float* A[3];
    const unsigned short* Wt[3];
    const float* bias[3];
    void* C[3];
};

__global__ __launch_bounds__(256, 2) void qkv_fill_k(GemmArgs ga, float* __restrict__ attn_p) {
    __shared__ __align__(16) unsigned short lsA[128 * LDSTRIDE];
    __shared__ __align__(16) unsigned short lsB[128 * LDSTRIDE];
    if (blockIdx.x < 768) {
        const int f = blockIdx.x;
        const int z = f >> 8;
        const int xt = ((f >> 5) & 7) * 8 + (f & 7);
        const int yt = (f >> 3) & 3;
        gemm_tile<0>(ga.A[z], ga.Wt[z], ga.bias[z], ga.C[z], xt * 128, yt * 128, lsA, lsB);
        return;
    }
    const size_t n4 = (size_t)ATTN_ROWS * SEQ / 4;     // 33,554,432 f32x4
    const size_t stride = (size_t)1024 * 256;
    size_t i = (size_t)(blockIdx.x - 768) * 256 + threadIdx.x;
    f32x4 z = {0.f, 0.f, 0.f, 0.f};
    for (; i < n4; i += stride)
        __builtin_nontemporal_store(z, (f32x4*)attn_p + i);
}

// ---------------------------------------------------------------------------
// Band-attention compute: one block per (b,h,64-row t-tile). K/V rows
// [t0-16, t0+63] in LDS. Lane = (r=row 0..15, c=d-quarter 0..3). Writes
// f32 ctx (16MB) and the 17 band probs per row to pb [ATTN_ROWS][20] (ws).
// ---------------------------------------------------------------------------
#define KV_ROWS 80
#define LROW 72

__device__ __forceinline__ void load16f(const unsigned short* p, float* out) {
    bf16x8 a = *(const bf16x8*)p;
    bf16x8 b = *(const bf16x8*)(p + 8);
#pragma unroll
    for (int i = 0; i < 8; ++i) { out[i] = (float)a[i]; out[8 + i] = (float)b[i]; }
}

__global__ __launch_bounds__(256, 4) void attn3_k(
    const unsigned short* __restrict__ Q,
    const unsigned short* __restrict__ K,
    const unsigned short* __restrict__ V,
    const float* __restrict__ gamma_p,
    float* __restrict__ pb,
    float* __restrict__ ctx) {
    __shared__ __align__(16) unsigned short lk[KV_ROWS * LROW];
    __shared__ __align__(16) unsigned short lv[KV_ROWS * LROW];

    const int bh = blockIdx.y;
    const int t0 = blockIdx.x * 64;
    const int b = bh >> 3;
    const int h = bh & 7;
    const int tid = threadIdx.x;
    const int w = tid >> 6;
    const int lane = tid & 63;
    const int r = lane >> 2;
    const int c = lane & 3;

    const float g = gamma_p[0];
    const float rs = 0.044194173824159216f;   // 1/sqrt(512)

    const size_t srcbase = (size_t)b * SEQ * D_MODEL + (size_t)h * HDIM;
    for (int idx = tid; idx < KV_ROWS * 8; idx += 256) {
        const int row = idx >> 3;
        const int ch = (idx & 7) * 8;
        const int grow = t0 - 16 + row;
        uint4 kv4 = {0, 0, 0, 0};
        uint4 vv4 = {0, 0, 0, 0};
        if (grow >= 0) {
            const size_t off = srcbase + (size_t)grow * D_MODEL + ch;
            kv4 = *(const uint4*)&K[off];
            vv4 = *(const uint4*)&V[off];
        }
        *(uint4*)&lk[row * LROW + ch] = kv4;
        *(uint4*)&lv[row * LROW + ch] = vv4;
    }
    __syncthreads();

    const int gr = t0 + w * 16 + r;
    const size_t qoff = srcbase + (size_t)gr * D_MODEL + c * 16;
    float qv[16];
    load16f(&Q[qoff], qv);

    const int lr0 = w * 16 + r;
    float scr[17];
#pragma unroll
    for (int j = 0; j < 17; ++j) {
        float kvv[16];
        load16f(&lk[(lr0 + j) * LROW + c * 16], kvv);
        float part = 0.f;
#pragma unroll
        for (int i = 0; i < 16; ++i) part = fmaf(qv[i], kvv[i], part);
        part += __shfl_xor(part, 1, 64);
        part += __shfl_xor(part, 2, 64);
        const float dec = __expf(-g * (float)(16 - j));
        scr[j] = part * rs * dec;
        if (gr - 16 + j < 0) scr[j] = -__builtin_inff();
    }

    float m = scr[0];
#pragma unroll
    for (int j = 1; j < 17; ++j) m = fmaxf(m, scr[j]);
    float l = 0.f;
#pragma unroll
    for (int j = 0; j < 17; ++j) { scr[j] = __expf(scr[j] - m); l += scr[j]; }
    const float inv = 1.f / l;

    float acc[16];
#pragma unroll
    for (int i = 0; i < 16; ++i) acc[i] = 0.f;
#pragma unroll
    for (int j = 0; j < 17; ++j) {
        float vv[16];
        load16f(&lv[(lr0 + j) * LROW + c * 16], vv);
#pragma unroll
        for (int i = 0; i < 16; ++i) acc[i] = fmaf(scr[j], vv[i], acc[i]);
    }

    float* cp = &ctx[qoff];
#pragma unroll
    for (int i = 0; i < 16; i += 4) {
        f32x4 v = {acc[i] * inv, acc[i + 1] * inv, acc[i + 2] * inv, acc[i + 3] * inv};
        *(f32x4*)&cp[i] = v;
    }

    float* prow = &pb[((size_t)bh * SEQ + gr) * 20];
    for (int j = c; j < 17; j += 4) prow[j] = scr[j] * inv;
}

// ---------------------------------------------------------------------------
// K4: blocks 0..255 = output projection; blocks 256..511 = band-writer.
// Band-writer: one row per thread; rewrites only the <=6 f32x4 blocks that
// intersect the band [s_lo, t] (complete values, zeros in non-band lanes).
// ---------------------------------------------------------------------------
__global__ __launch_bounds__(256, 2) void fused_k(
    const float* __restrict__ Ctx,
    const unsigned short* __restrict__ WoT,
    const float* __restrict__ bo,
    float* __restrict__ out_p,
    const float* __restrict__ pb,
    float* __restrict__ attn_out) {
    __shared__ __align__(16) unsigned short lsA[128 * LDSTRIDE];
    __shared__ __align__(16) unsigned short lsB[128 * LDSTRIDE];

    if (blockIdx.x < 256) {
        const int f = blockIdx.x;
        const int xt = ((f >> 5) & 7) * 8 + (f & 7);
        const int yt = (f >> 3) & 3;
        gemm_tile<1>(Ctx, WoT, bo, out_p, xt * 128, yt * 128, lsA, lsB);
        return;
    }

    const int row = (blockIdx.x - 256) * 256 + threadIdx.x;   // 0..65535
    const int t = row & (SEQ - 1);
    const int s_lo = (t - 16 < 0) ? 0 : t - 16;
    const int lo4 = s_lo >> 2;
    const int hi4 = t >> 2;
    const float* prow = &pb[(size_t)row * 20];
    float* dst = &attn_out[(size_t)row * SEQ];
    for (int c4 = lo4; c4 <= hi4; ++c4) {
        const int col0 = c4 * 4;
        f32x4 v = {0.f, 0.f, 0.f, 0.f};
#pragma unroll
        for (int k = 0; k < 4; ++k) {
            const int col = col0 + k;
            v[k] = (col >= s_lo && col <= t) ? prow[col - (t - 16)] : 0.f;
        }
        __builtin_nontemporal_store(v, (f32x4*)&dst[col0]);
    }
}

// ---------------------------------------------------------------------------
// ws: [Qp|Kp|Vp bf16 3x8MB][WT bf16 4x512KB][Ctx f32 16MB][pb f32 5.2MB]
// ---------------------------------------------------------------------------
extern "C" void kernel_launch(void* const* d_in, const int* in_sizes, int n_in,
                              void* d_out, int out_size, void* d_ws, size_t ws_size,
                              hipStream_t stream) {
    const float* queries = (const float*)d_in[0];
    const float* keys    = (const float*)d_in[1];
    const float* values  = (const float*)d_in[2];
    // d_in[3] attn_mask: fixed causal triu — folded analytically.
    const float* Wq = (const float*)d_in[4];
    const float* bq = (const float*)d_in[5];
    const float* Wk = (const float*)d_in[6];
    const float* bk = (const float*)d_in[7];
    const float* Wv = (const float*)d_in[8];
    const float* bv = (const float*)d_in[9];
    const float* Wo = (const float*)d_in[10];
    const float* bo = (const float*)d_in[11];
    const float* gamma = (const float*)d_in[12];

    char* ws = (char*)d_ws;
    unsigned short* Qp  = (unsigned short*)ws;
    unsigned short* Kp  = Qp + PROJ_ELEMS;
    unsigned short* Vp  = Kp + PROJ_ELEMS;
    unsigned short* WT  = Vp + PROJ_ELEMS;
    unsigned short* WqT = WT;
    unsigned short* WkT = WT + 262144;
    unsigned short* WvT = WT + 2 * 262144;
    unsigned short* WoT = WT + 3 * 262144;
    float* Ctx = (float*)(WT + 4 * 262144);
    float* pb  = Ctx + PROJ_ELEMS;            // [ATTN_ROWS][20] f32

    float* out_p  = (float*)d_out;            // [8192,512] f32
    float* attn_p = out_p + PROJ_ELEMS;       // [65536,2048] f32

    // 1) weight transposes (f32 in, bf16 out)
    TransArgs ta;
    ta.W[0] = Wq;  ta.W[1] = Wk;  ta.W[2] = Wv;  ta.W[3] = Wo;
    ta.Wt[0] = WqT; ta.Wt[1] = WkT; ta.Wt[2] = WvT; ta.Wt[3] = WoT;
    transpose_k<<<dim3(16, 16, 4), dim3(32, 8), 0, stream>>>(ta);

    // 2) QKV GEMM (768) + full attn zero-fill (1024) in one launch
    GemmArgs gq;
    gq.A[0] = queries; gq.A[1] = keys;  gq.A[2] = values;
    gq.Wt[0] = WqT;    gq.Wt[1] = WkT;  gq.Wt[2] = WvT;
    gq.bias[0] = bq;   gq.bias[1] = bk; gq.bias[2] = bv;
    gq.C[0] = Qp;      gq.C[1] = Kp;    gq.C[2] = Vp;
    qkv_fill_k<<<1792, 256, 0, stream>>>(gq, attn_p);

    // 3) band-attention compute: ctx + band-prob table
    attn3_k<<<dim3(SEQ / 64, B_SZ * N_HEADS), 256, 0, stream>>>(
        Qp, Kp, Vp, gamma, pb, Ctx);

    // 4) out-projection (256) + band-writer (256)
    fused_k<<<512, 256, 0, stream>>>(Ctx, WoT, bo, out_p, pb, attn_p);
}

// Round 11
// 651.100 us; speedup vs baseline: 1.0337x; 1.0337x over previous
//
#include <hip/hip_runtime.h>
#include <hip/hip_bf16.h>
#include <cstdint>
#include <cstddef>

// AttentionLayerEnhance: B=4, L=S=2048, D=512, H=8, window=32.
// I/O: all inputs f32, both outputs f32. Internal: bf16 MFMA, f32 accum.
// Accounting (R3-R10): ~470us of dur_us is harness poison/restore; ours ~181us.
// Measured ladder: R7 XCD-swizzle+NT = neutral; R8 direct-global B = -20us
// regress; R9 out-proj||streamer fusion = +3us win (BEST, 651us); R10
// fill||GEMM overlap = -22us regress. This is R9 restored.
#define D_MODEL 512
#define N_HEADS 8
#define HDIM 64
#define SEQ 2048
#define B_SZ 4
#define M_TOT (B_SZ * SEQ)
#define ATTN_ROWS (B_SZ * N_HEADS * SEQ)
#define PROJ_ELEMS ((size_t)M_TOT * D_MODEL)

typedef __bf16 bf16x8 __attribute__((ext_vector_type(8)));
typedef float  f32x4  __attribute__((ext_vector_type(4)));

__device__ __forceinline__ unsigned short f2bf(float x) {
    __bf16 b = (__bf16)x;
    return __builtin_bit_cast(unsigned short, b);
}

// ---------------------------------------------------------------------------
// 512x512 transpose (f32 W[k][n] -> bf16 Wt[n][k]). z selects weight.
// ---------------------------------------------------------------------------
struct TransArgs {
    const float* W[4];
    unsigned short* Wt[4];
};

__global__ void transpose_k(TransArgs ta) {
    __shared__ float tile[32][33];
    const int z = blockIdx.z;
    const float* W = ta.W[z];
    unsigned short* Wt = ta.Wt[z];
    int x = blockIdx.x * 32 + threadIdx.x;
    int y0 = blockIdx.y * 32;
    for (int j = threadIdx.y; j < 32; j += 8)
        tile[j][threadIdx.x] = W[(size_t)(y0 + j) * D_MODEL + x];
    __syncthreads();
    int xo = blockIdx.y * 32 + threadIdx.x;
    int yo0 = blockIdx.x * 32;
    for (int j = threadIdx.y; j < 32; j += 8)
        Wt[(size_t)(yo0 + j) * D_MODEL + xo] = f2bf(tile[threadIdx.x][j]);
}

#define LDSTRIDE 72

// ---------------------------------------------------------------------------
// GEMM tile body (R7-proven): C[128,128] tile of A[M,512]*W + bias.
// A: f32, staged->bf16 in LDS. B (Wt[N,K] bf16): LDS-staged.
// 4 waves (2x2 of 64x64), mfma_f32_16x16x32_bf16, 4x4 acc/wave.
// ---------------------------------------------------------------------------
template <int F32OUT>
__device__ __forceinline__ void gemm_tile(
    const float* __restrict__ A, const unsigned short* __restrict__ Wt,
    const float* __restrict__ bias, void* __restrict__ C,
    int m0, int n0, unsigned short* lsA, unsigned short* lsB) {
    const int tid = threadIdx.x;
    const int lane = tid & 63;
    const int wid = tid >> 6;
    const int wm = (wid >> 1) * 64;
    const int wn = (wid & 1) * 64;
    const int lrow = lane & 15;
    const int quad = lane >> 4;

    f32x4 acc[4][4];
#pragma unroll
    for (int i = 0; i < 4; ++i)
#pragma unroll
        for (int j = 0; j < 4; ++j)
            acc[i][j] = (f32x4){0.f, 0.f, 0.f, 0.f};

    for (int kt = 0; kt < D_MODEL; kt += 64) {
        __syncthreads();
#pragma unroll
        for (int p = 0; p < 4; ++p) {
            int c = p * 256 + tid;
            int r = c >> 3;
            int col = (c & 7) << 3;
            const float* src = &A[(size_t)(m0 + r) * D_MODEL + kt + col];
            float4 a0 = *(const float4*)src;
            float4 a1 = *(const float4*)(src + 4);
            unsigned short t8[8];
            t8[0] = f2bf(a0.x); t8[1] = f2bf(a0.y); t8[2] = f2bf(a0.z); t8[3] = f2bf(a0.w);
            t8[4] = f2bf(a1.x); t8[5] = f2bf(a1.y); t8[6] = f2bf(a1.z); t8[7] = f2bf(a1.w);
            *(uint4*)&lsA[r * LDSTRIDE + col] = *(const uint4*)t8;
        }
#pragma unroll
        for (int p = 0; p < 4; ++p) {
            int c = p * 256 + tid;
            int r = c >> 3;
            int col = (c & 7) << 3;
            *(uint4*)&lsB[r * LDSTRIDE + col] =
                *(const uint4*)&Wt[(size_t)(n0 + r) * D_MODEL + kt + col];
        }
        __syncthreads();
#pragma unroll
        for (int ks = 0; ks < 2; ++ks) {
            const int ko = ks * 32 + quad * 8;
            bf16x8 af[4], bfr[4];
#pragma unroll
            for (int mt = 0; mt < 4; ++mt)
                af[mt] = *(const bf16x8*)&lsA[(wm + mt * 16 + lrow) * LDSTRIDE + ko];
#pragma unroll
            for (int nt = 0; nt < 4; ++nt)
                bfr[nt] = *(const bf16x8*)&lsB[(wn + nt * 16 + lrow) * LDSTRIDE + ko];
#pragma unroll
            for (int mt = 0; mt < 4; ++mt)
#pragma unroll
                for (int nt = 0; nt < 4; ++nt)
                    acc[mt][nt] = __builtin_amdgcn_mfma_f32_16x16x32_bf16(
                        af[mt], bfr[nt], acc[mt][nt], 0, 0, 0);
        }
    }

    // Epilogue: C/D layout col=lane&15, row=quad*4+reg (m89-verified).
#pragma unroll
    for (int nt = 0; nt < 4; ++nt) {
        const int gcol = n0 + wn + nt * 16 + lrow;
        const float bv = bias[gcol];
#pragma unroll
        for (int mt = 0; mt < 4; ++mt) {
            const int grow = m0 + wm + mt * 16 + quad * 4;
#pragma unroll
            for (int r = 0; r < 4; ++r) {
                const float v = acc[mt][nt][r] + bv;
                if (F32OUT)
                    __builtin_nontemporal_store(
                        v, &((float*)C)[(size_t)(grow + r) * D_MODEL + gcol]);
                else
                    ((unsigned short*)C)[(size_t)(grow + r) * D_MODEL + gcol] = f2bf(v);
            }
        }
    }
}

// ---------------------------------------------------------------------------
// QKV projections: 768 blocks, z = which of {Q,K,V}; XCD-friendly decode.
// ---------------------------------------------------------------------------
struct GemmArgs {
    const float* A[3];
    const unsigned short* Wt[3];
    const float* bias[3];
    void* C[3];
};

__global__ __launch_bounds__(256, 2) void gemm_qkv(GemmArgs ga) {
    __shared__ __align__(16) unsigned short lsA[128 * LDSTRIDE];
    __shared__ __align__(16) unsigned short lsB[128 * LDSTRIDE];
    const int f = blockIdx.x;
    const int z = f >> 8;
    const int xt = ((f >> 5) & 7) * 8 + (f & 7);
    const int yt = (f >> 3) & 3;
    gemm_tile<0>(ga.A[z], ga.Wt[z], ga.bias[z], ga.C[z], xt * 128, yt * 128, lsA, lsB);
}

// ---------------------------------------------------------------------------
// Band-attention compute: one block per (b,h,64-row t-tile). K/V rows
// [t0-16, t0+63] in LDS. Lane = (r=row 0..15, c=d-quarter 0..3). Writes
// f32 ctx (16MB) and the 17 band probs per row to pb [ATTN_ROWS][20] (ws).
// ---------------------------------------------------------------------------
#define KV_ROWS 80
#define LROW 72

__device__ __forceinline__ void load16f(const unsigned short* p, float* out) {
    bf16x8 a = *(const bf16x8*)p;
    bf16x8 b = *(const bf16x8*)(p + 8);
#pragma unroll
    for (int i = 0; i < 8; ++i) { out[i] = (float)a[i]; out[8 + i] = (float)b[i]; }
}

__global__ __launch_bounds__(256, 4) void attn3_k(
    const unsigned short* __restrict__ Q,
    const unsigned short* __restrict__ K,
    const unsigned short* __restrict__ V,
    const float* __restrict__ gamma_p,
    float* __restrict__ pb,
    float* __restrict__ ctx) {
    __shared__ __align__(16) unsigned short lk[KV_ROWS * LROW];
    __shared__ __align__(16) unsigned short lv[KV_ROWS * LROW];

    const int bh = blockIdx.y;
    const int t0 = blockIdx.x * 64;
    const int b = bh >> 3;
    const int h = bh & 7;
    const int tid = threadIdx.x;
    const int w = tid >> 6;
    const int lane = tid & 63;
    const int r = lane >> 2;
    const int c = lane & 3;

    const float g = gamma_p[0];
    const float rs = 0.044194173824159216f;   // 1/sqrt(512)

    const size_t srcbase = (size_t)b * SEQ * D_MODEL + (size_t)h * HDIM;
    for (int idx = tid; idx < KV_ROWS * 8; idx += 256) {
        const int row = idx >> 3;
        const int ch = (idx & 7) * 8;
        const int grow = t0 - 16 + row;
        uint4 kv4 = {0, 0, 0, 0};
        uint4 vv4 = {0, 0, 0, 0};
        if (grow >= 0) {
            const size_t off = srcbase + (size_t)grow * D_MODEL + ch;
            kv4 = *(const uint4*)&K[off];
            vv4 = *(const uint4*)&V[off];
        }
        *(uint4*)&lk[row * LROW + ch] = kv4;
        *(uint4*)&lv[row * LROW + ch] = vv4;
    }
    __syncthreads();

    const int gr = t0 + w * 16 + r;
    const size_t qoff = srcbase + (size_t)gr * D_MODEL + c * 16;
    float qv[16];
    load16f(&Q[qoff], qv);

    const int lr0 = w * 16 + r;
    float scr[17];
#pragma unroll
    for (int j = 0; j < 17; ++j) {
        float kvv[16];
        load16f(&lk[(lr0 + j) * LROW + c * 16], kvv);
        float part = 0.f;
#pragma unroll
        for (int i = 0; i < 16; ++i) part = fmaf(qv[i], kvv[i], part);
        part += __shfl_xor(part, 1, 64);
        part += __shfl_xor(part, 2, 64);
        const float dec = __expf(-g * (float)(16 - j));
        scr[j] = part * rs * dec;
        if (gr - 16 + j < 0) scr[j] = -__builtin_inff();
    }

    float m = scr[0];
#pragma unroll
    for (int j = 1; j < 17; ++j) m = fmaxf(m, scr[j]);
    float l = 0.f;
#pragma unroll
    for (int j = 0; j < 17; ++j) { scr[j] = __expf(scr[j] - m); l += scr[j]; }
    const float inv = 1.f / l;

    float acc[16];
#pragma unroll
    for (int i = 0; i < 16; ++i) acc[i] = 0.f;
#pragma unroll
    for (int j = 0; j < 17; ++j) {
        float vv[16];
        load16f(&lv[(lr0 + j) * LROW + c * 16], vv);
#pragma unroll
        for (int i = 0; i < 16; ++i) acc[i] = fmaf(scr[j], vv[i], acc[i]);
    }

    float* cp = &ctx[qoff];
#pragma unroll
    for (int i = 0; i < 16; i += 4) {
        f32x4 v = {acc[i] * inv, acc[i + 1] * inv, acc[i + 2] * inv, acc[i + 3] * inv};
        *(f32x4*)&cp[i] = v;
    }

    // Band probs -> ws table [ATTN_ROWS][20].
    float* prow = &pb[((size_t)bh * SEQ + gr) * 20];
    for (int j = c; j < 17; j += 4) prow[j] = scr[j] * inv;
}

// ---------------------------------------------------------------------------
// Fused: blocks 0..255 = output projection (compute-bound, R7 GEMM body);
// blocks 256..1279 = attn row-streamer (memory-bound, 537MB NT stores).
// Out-proj blocks dispatch FIRST so they're resident while writers fill BW.
// ---------------------------------------------------------------------------
__global__ __launch_bounds__(256, 2) void fused_k(
    const float* __restrict__ Ctx,
    const unsigned short* __restrict__ WoT,
    const float* __restrict__ bo,
    float* __restrict__ out_p,
    const float* __restrict__ pb,
    float* __restrict__ attn_out) {
    __shared__ __align__(16) unsigned short lsA[128 * LDSTRIDE];
    __shared__ __align__(16) unsigned short lsB[128 * LDSTRIDE];

    if (blockIdx.x < 256) {
        const int f = blockIdx.x;
        const int xt = ((f >> 5) & 7) * 8 + (f & 7);
        const int yt = (f >> 3) & 3;
        gemm_tile<1>(Ctx, WoT, bo, out_p, xt * 128, yt * 128, lsA, lsB);
        return;
    }

    const int wb = blockIdx.x - 256;           // 0..1023
    const int bh = wb >> 5;                    // 0..31
    const int t0 = (wb & 31) * 64;
    const int tid = threadIdx.x;

    const size_t rowbase = ((size_t)bh * SEQ + t0) * SEQ;
    const size_t prowbase = ((size_t)bh * SEQ + t0) * 20;
    for (int i = tid; i < 64 * 512; i += 256) {
        const int row = i >> 9;                // 0..63
        const int c4 = i & 511;                // f32x4 index in row
        const int t = t0 + row;
        const int s_lo = (t - 16 < 0) ? 0 : t - 16;
        const int lo4 = s_lo >> 2;
        const int hi4 = t >> 2;
        f32x4 v = {0.f, 0.f, 0.f, 0.f};
        if ((unsigned)(c4 - lo4) <= (unsigned)(hi4 - lo4)) {
            const float* prow = &pb[prowbase + (size_t)row * 20];
            const int col0 = c4 * 4;
#pragma unroll
            for (int k = 0; k < 4; ++k) {
                const int col = col0 + k;
                v[k] = (col >= s_lo && col <= t) ? prow[col - (t - 16)] : 0.f;
            }
        }
        __builtin_nontemporal_store(
            v, (f32x4*)&attn_out[rowbase + (size_t)row * SEQ + (c4 << 2)]);
    }
}

// ---------------------------------------------------------------------------
// ws: [Qp|Kp|Vp bf16 3x8MB][WT bf16 4x512KB][Ctx f32 16MB][pb f32 5.2MB]
// ---------------------------------------------------------------------------
extern "C" void kernel_launch(void* const* d_in, const int* in_sizes, int n_in,
                              void* d_out, int out_size, void* d_ws, size_t ws_size,
                              hipStream_t stream) {
    const float* queries = (const float*)d_in[0];
    const float* keys    = (const float*)d_in[1];
    const float* values  = (const float*)d_in[2];
    // d_in[3] attn_mask: fixed causal triu — folded analytically.
    const float* Wq = (const float*)d_in[4];
    const float* bq = (const float*)d_in[5];
    const float* Wk = (const float*)d_in[6];
    const float* bk = (const float*)d_in[7];
    const float* Wv = (const float*)d_in[8];
    const float* bv = (const float*)d_in[9];
    const float* Wo = (const float*)d_in[10];
    const float* bo = (const float*)d_in[11];
    const float* gamma = (const float*)d_in[12];

    char* ws = (char*)d_ws;
    unsigned short* Qp  = (unsigned short*)ws;
    unsigned short* Kp  = Qp + PROJ_ELEMS;
    unsigned short* Vp  = Kp + PROJ_ELEMS;
    unsigned short* WT  = Vp + PROJ_ELEMS;
    unsigned short* WqT = WT;
    unsigned short* WkT = WT + 262144;
    unsigned short* WvT = WT + 2 * 262144;
    unsigned short* WoT = WT + 3 * 262144;
    float* Ctx = (float*)(WT + 4 * 262144);
    float* pb  = Ctx + PROJ_ELEMS;            // [ATTN_ROWS][20] f32

    float* out_p  = (float*)d_out;            // [8192,512] f32
    float* attn_p = out_p + PROJ_ELEMS;       // [65536,2048] f32

    // 1) weight transposes (f32 in, bf16 out)
    TransArgs ta;
    ta.W[0] = Wq;  ta.W[1] = Wk;  ta.W[2] = Wv;  ta.W[3] = Wo;
    ta.Wt[0] = WqT; ta.Wt[1] = WkT; ta.Wt[2] = WvT; ta.Wt[3] = WoT;
    transpose_k<<<dim3(16, 16, 4), dim3(32, 8), 0, stream>>>(ta);

    // 2) fused QKV projections (R7 GEMM: A+B LDS-staged)
    GemmArgs gq;
    gq.A[0] = queries; gq.A[1] = keys;  gq.A[2] = values;
    gq.Wt[0] = WqT;    gq.Wt[1] = WkT;  gq.Wt[2] = WvT;
    gq.bias[0] = bq;   gq.bias[1] = bk; gq.bias[2] = bv;
    gq.C[0] = Qp;      gq.C[1] = Kp;    gq.C[2] = Vp;
    gemm_qkv<<<768, 256, 0, stream>>>(gq);

    // 3) band-attention compute: ctx + band-prob table
    attn3_k<<<dim3(SEQ / 64, B_SZ * N_HEADS), 256, 0, stream>>>(
        Qp, Kp, Vp, gamma, pb, Ctx);

    // 4) fused out-projection (256 blocks) + attn row-streamer (1024 blocks)
    fused_k<<<512 + 768, 256, 0, stream>>>(Ctx, WoT, bo, out_p, pb, attn_p);
}